// Round 1
// baseline (94.275 us; speedup 1.0000x reference)
//
#include <hip/hip_runtime.h>
#include <hip/hip_bf16.h>

// DeViSE: logits = img@Wcls^T + b ; V = relu(img@Wvis^T+b) ; S = relu(E@Wsem^T+b) ;
// scores = V@S^T.  All GEMMs in bf16 MFMA (16x16x32), f32 accumulate.
//
// Workspace layout (bytes):
//   imgB  [2048][2048] bf16 @ 0          (8,388,608)
//   WcomB [2048][2048] bf16 @ 8,388,608  (rows 0-999 Wcls, 1000-1023 zero, 1024+ Wvis)
//   Vb    [2048][1024] bf16 @ 16,777,216
//   Sb    [1024][1024] bf16 @ 20,971,520
//   wordB [1024][320]  bf16 @ 23,068,672 (zero-padded rows>=1000, cols>=300)
//   WsemB [1024][320]  bf16 @ 23,724,032 (zero-padded cols>=300)
//   total 24,379,392 B

typedef __bf16 bf16x8 __attribute__((ext_vector_type(8)));
typedef float  f32x4  __attribute__((ext_vector_type(4)));

#define GLOAD_LDS16(gptr, lptr)                                                   \
  __builtin_amdgcn_global_load_lds((__attribute__((address_space(1))) void*)(gptr), \
                                   (__attribute__((address_space(3))) void*)(lptr), \
                                   16, 0, 0)

// ---------------- convert kernels (f32 -> bf16, with padding) ----------------

__global__ void cvt_plain_k(const float* __restrict__ src, __bf16* __restrict__ dst, int n8) {
  int i = blockIdx.x * 256 + threadIdx.x;
  if (i >= n8) return;
  const float4* s = (const float4*)src;
  float4 x = s[i * 2], y = s[i * 2 + 1];
  bf16x8 o;
  o[0] = (__bf16)x.x; o[1] = (__bf16)x.y; o[2] = (__bf16)x.z; o[3] = (__bf16)x.w;
  o[4] = (__bf16)y.x; o[5] = (__bf16)y.y; o[6] = (__bf16)y.z; o[7] = (__bf16)y.w;
  ((bf16x8*)dst)[i] = o;
}

// dst [2048][2048]: rows 0-999 <- Wcls, 1000-1023 <- 0, 1024-2047 <- Wvis
__global__ void cvt_comb_k(const float* __restrict__ Wcls, const float* __restrict__ Wvis,
                           __bf16* __restrict__ dst) {
  int i = blockIdx.x * 256 + threadIdx.x;   // chunk of 8; 524288 total
  if (i >= 524288) return;
  int row = i >> 8;              // 256 chunks per 2048-wide row
  int cc  = (i & 255) * 8;
  const float* src = nullptr;
  if (row < 1000)       src = Wcls + (size_t)row * 2048 + cc;
  else if (row >= 1024) src = Wvis + (size_t)(row - 1024) * 2048 + cc;
  bf16x8 o;
  if (src) {
    const float4* s = (const float4*)src;
    float4 x = s[0], y = s[1];
    o[0] = (__bf16)x.x; o[1] = (__bf16)x.y; o[2] = (__bf16)x.z; o[3] = (__bf16)x.w;
    o[4] = (__bf16)y.x; o[5] = (__bf16)y.y; o[6] = (__bf16)y.z; o[7] = (__bf16)y.w;
  } else {
    for (int j = 0; j < 8; ++j) o[j] = (__bf16)0.f;
  }
  ((bf16x8*)dst)[i] = o;
}

// dst [1024][320], src [rows_src][cols_src], zero-pad outside
__global__ void cvt_pad_k(const float* __restrict__ src, __bf16* __restrict__ dst,
                          int rows_src, int cols_src) {
  int i = blockIdx.x * 256 + threadIdx.x;
  if (i >= 1024 * 320) return;
  int r = i / 320, c = i - r * 320;
  float v = (r < rows_src && c < cols_src) ? src[(size_t)r * cols_src + c] : 0.f;
  dst[i] = (__bf16)v;
}

// ---------------- bf16 GEMM, C = A @ B^T  (m97-style 128x128 tile) ----------------
// A: [M][K] bf16 row-major, Bm: [N][K] bf16 row-major. M,N multiples of 128, K of 32.
// EPI 0: col<1000 -> outF[row*1000+col]=acc+bias1[col];
//        col>=1024 -> outB[row*1024+col-1024]=bf16(relu(acc+bias2[col-1024]))
// EPI 1: outB[row*1024+col]=bf16(relu(acc+bias1[col]))
// EPI 2: col<1000 -> outF[row*1000+col]=acc
template <int EPI>
__global__ void gemm_bt_k(const __bf16* __restrict__ A, const __bf16* __restrict__ Bm,
                          const float* __restrict__ bias1, const float* __restrict__ bias2,
                          float* __restrict__ outF, __bf16* __restrict__ outB, int K) {
  __shared__ __align__(16) __bf16 At[128 * 32];
  __shared__ __align__(16) __bf16 Bt[128 * 32];
  const int tid  = threadIdx.x;
  const int lane = tid & 63;
  const int wv   = tid >> 6;       // 4 waves
  const int wr   = wv >> 1, wc = wv & 1;   // 2x2 wave grid, each 64x64
  const int bm = blockIdx.y, bn = blockIdx.x;

  f32x4 acc[4][4];
#pragma unroll
  for (int m = 0; m < 4; ++m)
#pragma unroll
    for (int n = 0; n < 4; ++n) acc[m][n] = (f32x4){0.f, 0.f, 0.f, 0.f};

  const int nkt = K >> 5;
  for (int kt = 0; kt < nkt; ++kt) {
#pragma unroll
    for (int j = 0; j < 2; ++j) {
      int idx = (wv * 2 + j) * 64 + lane;     // 16B chunk id, 512 per tile
      int r = idx >> 2, c8 = (idx & 3) * 8;   // tile row, k-elem offset
      const __bf16* ga = A  + ((size_t)(bm * 128 + r) * K + kt * 32 + c8);
      const __bf16* gb = Bm + ((size_t)(bn * 128 + r) * K + kt * 32 + c8);
      GLOAD_LDS16(ga, (char*)At + (wv * 2 + j) * 1024);
      GLOAD_LDS16(gb, (char*)Bt + (wv * 2 + j) * 1024);
    }
    __syncthreads();   // compiler drains vmcnt before barrier

    bf16x8 af[4], bfr[4];
    const bf16x8* Ap = (const bf16x8*)At;
    const bf16x8* Bp = (const bf16x8*)Bt;
#pragma unroll
    for (int m = 0; m < 4; ++m) af[m]  = Ap[(wr * 64 + m * 16 + (lane & 15)) * 4 + (lane >> 4)];
#pragma unroll
    for (int n = 0; n < 4; ++n) bfr[n] = Bp[(wc * 64 + n * 16 + (lane & 15)) * 4 + (lane >> 4)];
#pragma unroll
    for (int m = 0; m < 4; ++m)
#pragma unroll
      for (int n = 0; n < 4; ++n)
        acc[m][n] = __builtin_amdgcn_mfma_f32_16x16x32_bf16(af[m], bfr[n], acc[m][n], 0, 0, 0);
    __syncthreads();
  }

  // epilogue: C/D layout col=lane&15, row=(lane>>4)*4+j (m89/m91-verified)
#pragma unroll
  for (int m = 0; m < 4; ++m) {
    const int row0 = bm * 128 + wr * 64 + m * 16 + ((lane >> 4) << 2);
#pragma unroll
    for (int n = 0; n < 4; ++n) {
      const int col = bn * 128 + wc * 64 + n * 16 + (lane & 15);
      if (EPI == 0) {
        if (col < 1000) {
          const float bz = bias1[col];
#pragma unroll
          for (int j = 0; j < 4; ++j)
            outF[(size_t)(row0 + j) * 1000 + col] = acc[m][n][j] + bz;
        } else if (col >= 1024) {
          const float bz = bias2[col - 1024];
#pragma unroll
          for (int j = 0; j < 4; ++j) {
            float v = acc[m][n][j] + bz;
            outB[(size_t)(row0 + j) * 1024 + (col - 1024)] = (__bf16)fmaxf(v, 0.f);
          }
        }
      } else if (EPI == 1) {
        const float bz = bias1[col];
#pragma unroll
        for (int j = 0; j < 4; ++j) {
          float v = acc[m][n][j] + bz;
          outB[(size_t)(row0 + j) * 1024 + col] = (__bf16)fmaxf(v, 0.f);
        }
      } else {
        if (col < 1000) {
#pragma unroll
          for (int j = 0; j < 4; ++j)
            outF[(size_t)(row0 + j) * 1000 + col] = acc[m][n][j];
        }
      }
    }
  }
}

// ---------------- launch ----------------

extern "C" void kernel_launch(void* const* d_in, const int* in_sizes, int n_in,
                              void* d_out, int out_size, void* d_ws, size_t ws_size,
                              hipStream_t stream) {
  const float* image = (const float*)d_in[0];   // [2048][2048]
  const float* wemb  = (const float*)d_in[1];   // [1000][300]
  const float* Wcls  = (const float*)d_in[2];   // [1000][2048]
  const float* bcls  = (const float*)d_in[3];   // [1000]
  const float* Wvis  = (const float*)d_in[4];   // [1024][2048]
  const float* bvis  = (const float*)d_in[5];   // [1024]
  const float* Wsem  = (const float*)d_in[6];   // [1024][300]
  const float* bsem  = (const float*)d_in[7];   // [1024]

  float* logits = (float*)d_out;                      // [2048][1000]
  float* scores = logits + (size_t)2048 * 1000;       // [2048][1000]

  char* ws = (char*)d_ws;
  __bf16* imgB  = (__bf16*)(ws);
  __bf16* WcomB = (__bf16*)(ws + 8388608);
  __bf16* Vb    = (__bf16*)(ws + 16777216);
  __bf16* Sb    = (__bf16*)(ws + 20971520);
  __bf16* wordB = (__bf16*)(ws + 23068672);
  __bf16* WsemB = (__bf16*)(ws + 23724032);

  cvt_plain_k<<<2048, 256, 0, stream>>>(image, imgB, 524288);
  cvt_comb_k<<<2048, 256, 0, stream>>>(Wcls, Wvis, WcomB);
  cvt_pad_k<<<1280, 256, 0, stream>>>(wemb, wordB, 1000, 300);
  cvt_pad_k<<<1280, 256, 0, stream>>>(Wsem, WsemB, 1024, 300);

  // fused logits+V: [2048 x 2048pad] = imgB @ WcomB^T, K=2048
  gemm_bt_k<0><<<dim3(16, 16), 256, 0, stream>>>(imgB, WcomB, bcls, bvis, logits, Vb, 2048);
  // S: [1024pad x 1024] = wordB @ WsemB^T, K=320
  gemm_bt_k<1><<<dim3(8, 8), 256, 0, stream>>>(wordB, WsemB, bsem, nullptr, nullptr, Sb, 320);
  // scores: [2048 x 1024pad] = Vb @ Sb^T, K=1024 (store cols < 1000)
  gemm_bt_k<2><<<dim3(8, 16), 256, 0, stream>>>(Vb, Sb, nullptr, nullptr, scores, nullptr, 1024);
}

// Round 2
// 88.728 us; speedup vs baseline: 1.0625x; 1.0625x over previous
//
#include <hip/hip_runtime.h>
#include <hip/hip_bf16.h>

// DeViSE bf16-MFMA. Round 2: 2-phase double-buffered staging (issue next-tile
// global_load_lds BEFORE compute; single barrier per K-step), all-CU grids for
// every GEMM, converts merged into one dispatch.
//
// Workspace layout (bytes):
//   imgB  [2048][2048] bf16 @ 0
//   WcomB [2048][2048] bf16 @ 8,388,608   (rows 0-999 Wcls, 1000-1023 zero, 1024+ Wvis)
//   Vb    [2048][1024] bf16 @ 16,777,216
//   Sb    [1024][1024] bf16 @ 20,971,520
//   wordB [1024][320]  bf16 @ 23,068,672  (zero-pad rows>=1000, cols>=300)
//   WsemB [1024][320]  bf16 @ 23,724,032  (zero-pad cols>=300)

typedef __bf16 bf16x8 __attribute__((ext_vector_type(8)));
typedef float  f32x4  __attribute__((ext_vector_type(4)));

#define GLOAD_LDS16(gptr, lptr)                                                     \
  __builtin_amdgcn_global_load_lds((__attribute__((address_space(1))) void*)(gptr), \
                                   (__attribute__((address_space(3))) void*)(lptr), \
                                   16, 0, 0)

// ---------------- merged convert kernel ----------------
__device__ __forceinline__ bf16x8 cvt8(const float* src) {
  const float4* s = (const float4*)src;
  float4 x = s[0], y = s[1];
  bf16x8 o;
  o[0] = (__bf16)x.x; o[1] = (__bf16)x.y; o[2] = (__bf16)x.z; o[3] = (__bf16)x.w;
  o[4] = (__bf16)y.x; o[5] = (__bf16)y.y; o[6] = (__bf16)y.z; o[7] = (__bf16)y.w;
  return o;
}

__global__ void cvt_all_k(const float* __restrict__ image, const float* __restrict__ Wcls,
                          const float* __restrict__ Wvis, const float* __restrict__ wemb,
                          const float* __restrict__ Wsem,
                          __bf16* __restrict__ imgB, __bf16* __restrict__ WcomB,
                          __bf16* __restrict__ wordB, __bf16* __restrict__ WsemB) {
  const int blk = blockIdx.x, tid = threadIdx.x;
  if (blk < 2048) {                       // image -> imgB, 8-elem chunks
    int i = blk * 256 + tid;              // < 524288
    ((bf16x8*)imgB)[i] = cvt8(image + (size_t)i * 8);
  } else if (blk < 4096) {                // Wcls/Wvis -> WcomB (padded rows 1000-1023)
    int i = (blk - 2048) * 256 + tid;     // < 524288
    int row = i >> 8, cc = (i & 255) * 8;
    bf16x8 o;
    if (row < 1000)       o = cvt8(Wcls + (size_t)row * 2048 + cc);
    else if (row >= 1024) o = cvt8(Wvis + (size_t)(row - 1024) * 2048 + cc);
    else { for (int j = 0; j < 8; ++j) o[j] = (__bf16)0.f; }
    ((bf16x8*)WcomB)[i] = o;
  } else if (blk < 5376) {                // wemb -> wordB [1024][320]
    int i = (blk - 4096) * 256 + tid;     // < 327680
    int r = i / 320, c = i - r * 320;
    float v = (r < 1000 && c < 300) ? wemb[(size_t)r * 300 + c] : 0.f;
    wordB[i] = (__bf16)v;
  } else {                                // Wsem -> WsemB [1024][320]
    int i = (blk - 5376) * 256 + tid;     // < 327680
    int r = i / 320, c = i - r * 320;
    float v = (c < 300) ? Wsem[(size_t)r * 300 + c] : 0.f;
    WsemB[i] = (__bf16)v;
  }
}

// ---------------- bf16 GEMM, C = A @ B^T, 2-phase double-buffered ----------------
// Block tile = (WM*64) x (WN*64), WM*WN waves, each wave a 64x64 sub-tile.
// EPI 0: col<1000 -> outF[row*1000+col]=acc+bias1[col];
//        col>=1024 -> outB[row*1024+col-1024]=bf16(relu(acc+bias2[col-1024]))
// EPI 1: outB[row*1024+col]=bf16(relu(acc+bias1[col]))
// EPI 2: col<1000 -> outF[row*1000+col]=acc
template <int WM, int WN, int EPI>
__global__ void gemm_bt_k(const __bf16* __restrict__ A, const __bf16* __restrict__ Bm,
                          const float* __restrict__ bias1, const float* __restrict__ bias2,
                          float* __restrict__ outF, __bf16* __restrict__ outB, int K) {
  constexpr int BM = WM * 64, BN = WN * 64, NTHR = WM * WN * 64;
  __shared__ __align__(16) __bf16 At[2][BM * 32];
  __shared__ __align__(16) __bf16 Bt[2][BN * 32];
  const int tid  = threadIdx.x;
  const int lane = tid & 63;
  const int wv   = tid >> 6;
  const int wr   = wv / WN, wc = wv % WN;
  const int bm = blockIdx.y, bn = blockIdx.x;

  f32x4 acc[4][4];
#pragma unroll
  for (int m = 0; m < 4; ++m)
#pragma unroll
    for (int n = 0; n < 4; ++n) acc[m][n] = (f32x4){0.f, 0.f, 0.f, 0.f};

  const __bf16* Ab = A  + (size_t)(bm * BM) * K;
  const __bf16* Bb = Bm + (size_t)(bn * BN) * K;

#define STAGE(buf, kt)                                                         \
  do {                                                                         \
    _Pragma("unroll")                                                          \
    for (int j = 0; j < BM * 4 / NTHR; ++j) {                                  \
      int idx = j * NTHR + tid;                                                \
      int r = idx >> 2, c8 = (idx & 3) * 8;                                    \
      GLOAD_LDS16(Ab + (size_t)r * K + (kt) * 32 + c8, (char*)At[buf] + idx * 16); \
    }                                                                          \
    _Pragma("unroll")                                                          \
    for (int j = 0; j < BN * 4 / NTHR; ++j) {                                  \
      int idx = j * NTHR + tid;                                                \
      int r = idx >> 2, c8 = (idx & 3) * 8;                                    \
      GLOAD_LDS16(Bb + (size_t)r * K + (kt) * 32 + c8, (char*)Bt[buf] + idx * 16); \
    }                                                                          \
  } while (0)

  const int nkt = K >> 5;
  STAGE(0, 0);
  __syncthreads();           // compiler drains vmcnt(0) before s_barrier

  int cur = 0;
  for (int kt = 0; kt < nkt; ++kt) {
    if (kt + 1 < nkt) STAGE(cur ^ 1, kt + 1);   // in flight during compute

    const bf16x8* Ap = (const bf16x8*)At[cur];
    const bf16x8* Bp = (const bf16x8*)Bt[cur];
    bf16x8 af[4], bfr[4];
#pragma unroll
    for (int m = 0; m < 4; ++m) af[m]  = Ap[(wr * 64 + m * 16 + (lane & 15)) * 4 + (lane >> 4)];
#pragma unroll
    for (int n = 0; n < 4; ++n) bfr[n] = Bp[(wc * 64 + n * 16 + (lane & 15)) * 4 + (lane >> 4)];
#pragma unroll
    for (int m = 0; m < 4; ++m)
#pragma unroll
      for (int n = 0; n < 4; ++n)
        acc[m][n] = __builtin_amdgcn_mfma_f32_16x16x32_bf16(af[m], bfr[n], acc[m][n], 0, 0, 0);

    __syncthreads();         // single barrier: drains next-tile loads + read-done
    cur ^= 1;
  }
#undef STAGE

  // epilogue: C/D layout col=lane&15, row=(lane>>4)*4+j (m89/m91-verified)
#pragma unroll
  for (int m = 0; m < 4; ++m) {
    const int row0 = bm * BM + wr * 64 + m * 16 + ((lane >> 4) << 2);
#pragma unroll
    for (int n = 0; n < 4; ++n) {
      const int col = bn * BN + wc * 64 + n * 16 + (lane & 15);
      if (EPI == 0) {
        if (col < 1000) {
          const float bz = bias1[col];
#pragma unroll
          for (int j = 0; j < 4; ++j)
            outF[(size_t)(row0 + j) * 1000 + col] = acc[m][n][j] + bz;
        } else if (col >= 1024) {
          const float bz = bias2[col - 1024];
#pragma unroll
          for (int j = 0; j < 4; ++j) {
            float v = acc[m][n][j] + bz;
            outB[(size_t)(row0 + j) * 1024 + (col - 1024)] = (__bf16)fmaxf(v, 0.f);
          }
        }
      } else if (EPI == 1) {
        const float bz = bias1[col];
#pragma unroll
        for (int j = 0; j < 4; ++j) {
          float v = acc[m][n][j] + bz;
          outB[(size_t)(row0 + j) * 1024 + col] = (__bf16)fmaxf(v, 0.f);
        }
      } else {
        if (col < 1000) {
#pragma unroll
          for (int j = 0; j < 4; ++j)
            outF[(size_t)(row0 + j) * 1000 + col] = acc[m][n][j];
        }
      }
    }
  }
}

// ---------------- launch ----------------

extern "C" void kernel_launch(void* const* d_in, const int* in_sizes, int n_in,
                              void* d_out, int out_size, void* d_ws, size_t ws_size,
                              hipStream_t stream) {
  const float* image = (const float*)d_in[0];
  const float* wemb  = (const float*)d_in[1];
  const float* Wcls  = (const float*)d_in[2];
  const float* bcls  = (const float*)d_in[3];
  const float* Wvis  = (const float*)d_in[4];
  const float* bvis  = (const float*)d_in[5];
  const float* Wsem  = (const float*)d_in[6];
  const float* bsem  = (const float*)d_in[7];

  float* logits = (float*)d_out;                  // [2048][1000]
  float* scores = logits + (size_t)2048 * 1000;   // [2048][1000]

  char* ws = (char*)d_ws;
  __bf16* imgB  = (__bf16*)(ws);
  __bf16* WcomB = (__bf16*)(ws + 8388608);
  __bf16* Vb    = (__bf16*)(ws + 16777216);
  __bf16* Sb    = (__bf16*)(ws + 20971520);
  __bf16* wordB = (__bf16*)(ws + 23068672);
  __bf16* WsemB = (__bf16*)(ws + 23724032);

  cvt_all_k<<<6656, 256, 0, stream>>>(image, Wcls, Wvis, wemb, Wsem,
                                      imgB, WcomB, wordB, WsemB);

  // fused logits+V: [2048 x 2048pad] = imgB @ WcomB^T, K=2048, 128x128 tiles, 256 blocks
  gemm_bt_k<2, 2, 0><<<dim3(16, 16), 256, 0, stream>>>(imgB, WcomB, bcls, bvis, logits, Vb, 2048);
  // S: [1024pad x 1024] = wordB @ WsemB^T, K=320, 64x128 tiles, 128 blocks
  gemm_bt_k<1, 2, 1><<<dim3(8, 16), 128, 0, stream>>>(wordB, WsemB, bsem, nullptr, nullptr, Sb, 320);
  // scores: [2048 x 1024pad] = Vb @ Sb^T, K=1024, 64x128 tiles, 256 blocks
  gemm_bt_k<1, 2, 2><<<dim3(8, 32), 128, 0, stream>>>(Vb, Sb, nullptr, nullptr, scores, nullptr, 1024);
}

// Round 3
// 74.878 us; speedup vs baseline: 1.2591x; 1.1850x over previous
//
#include <hip/hip_runtime.h>
#include <hip/hip_bf16.h>

// DeViSE bf16-MFMA. Round 3: counted-wait 2-phase pipeline — raw s_barrier +
// explicit `s_waitcnt vmcnt(0)` at loop top (loads fly across the barrier
// during compute), sched_barrier-pinned issue order ds_read -> STAGE -> MFMA.
//
// Workspace layout (bytes):
//   imgB  [2048][2048] bf16 @ 0
//   WcomB [2048][2048] bf16 @ 8,388,608   (rows 0-999 Wcls, 1000-1023 zero, 1024+ Wvis)
//   Vb    [2048][1024] bf16 @ 16,777,216
//   Sb    [1024][1024] bf16 @ 20,971,520
//   wordB [1024][320]  bf16 @ 23,068,672  (zero-pad rows>=1000, cols>=300)
//   WsemB [1024][320]  bf16 @ 23,724,032  (zero-pad cols>=300)

typedef __bf16 bf16x8 __attribute__((ext_vector_type(8)));
typedef float  f32x4  __attribute__((ext_vector_type(4)));

#define GLOAD_LDS16(gptr, lptr)                                                     \
  __builtin_amdgcn_global_load_lds((__attribute__((address_space(1))) void*)(gptr), \
                                   (__attribute__((address_space(3))) void*)(lptr), \
                                   16, 0, 0)

// ---------------- merged convert kernel ----------------
__device__ __forceinline__ bf16x8 cvt8(const float* src) {
  const float4* s = (const float4*)src;
  float4 x = s[0], y = s[1];
  bf16x8 o;
  o[0] = (__bf16)x.x; o[1] = (__bf16)x.y; o[2] = (__bf16)x.z; o[3] = (__bf16)x.w;
  o[4] = (__bf16)y.x; o[5] = (__bf16)y.y; o[6] = (__bf16)y.z; o[7] = (__bf16)y.w;
  return o;
}

__global__ void cvt_all_k(const float* __restrict__ image, const float* __restrict__ Wcls,
                          const float* __restrict__ Wvis, const float* __restrict__ wemb,
                          const float* __restrict__ Wsem,
                          __bf16* __restrict__ imgB, __bf16* __restrict__ WcomB,
                          __bf16* __restrict__ wordB, __bf16* __restrict__ WsemB) {
  const int blk = blockIdx.x, tid = threadIdx.x;
  if (blk < 2048) {                       // image -> imgB, 8-elem chunks
    int i = blk * 256 + tid;              // < 524288
    ((bf16x8*)imgB)[i] = cvt8(image + (size_t)i * 8);
  } else if (blk < 4096) {                // Wcls/Wvis -> WcomB (padded rows 1000-1023)
    int i = (blk - 2048) * 256 + tid;     // < 524288
    int row = i >> 8, cc = (i & 255) * 8;
    bf16x8 o;
    if (row < 1000)       o = cvt8(Wcls + (size_t)row * 2048 + cc);
    else if (row >= 1024) o = cvt8(Wvis + (size_t)(row - 1024) * 2048 + cc);
    else { for (int j = 0; j < 8; ++j) o[j] = (__bf16)0.f; }
    ((bf16x8*)WcomB)[i] = o;
  } else if (blk < 5376) {                // wemb -> wordB [1024][320]
    int i = (blk - 4096) * 256 + tid;     // < 327680
    int r = i / 320, c = i - r * 320;
    float v = (r < 1000 && c < 300) ? wemb[(size_t)r * 300 + c] : 0.f;
    wordB[i] = (__bf16)v;
  } else {                                // Wsem -> WsemB [1024][320]
    int i = (blk - 5376) * 256 + tid;     // < 327680
    int r = i / 320, c = i - r * 320;
    float v = (c < 300) ? Wsem[(size_t)r * 300 + c] : 0.f;
    WsemB[i] = (__bf16)v;
  }
}

// ---------------- bf16 GEMM, C = A @ B^T, counted-wait 2-phase ----------------
// Block tile = (WM*64) x (WN*64), WM*WN waves, each wave a 64x64 sub-tile.
// EPI 0: col<1000 -> outF[row*1000+col]=acc+bias1[col];
//        col>=1024 -> outB[row*1024+col-1024]=bf16(relu(acc+bias2[col-1024]))
// EPI 1: outB[row*1024+col]=bf16(relu(acc+bias1[col]))
// EPI 2: col<1000 -> outF[row*1000+col]=acc
template <int WM, int WN, int EPI>
__global__ void gemm_bt_k(const __bf16* __restrict__ A, const __bf16* __restrict__ Bm,
                          const float* __restrict__ bias1, const float* __restrict__ bias2,
                          float* __restrict__ outF, __bf16* __restrict__ outB, int K) {
  constexpr int BM = WM * 64, BN = WN * 64, NTHR = WM * WN * 64;
  __shared__ __align__(16) __bf16 At[2][BM * 32];
  __shared__ __align__(16) __bf16 Bt[2][BN * 32];
  const int tid  = threadIdx.x;
  const int lane = tid & 63;
  const int wv   = tid >> 6;
  const int wr   = wv / WN, wc = wv % WN;
  const int bm = blockIdx.y, bn = blockIdx.x;

  f32x4 acc[4][4];
#pragma unroll
  for (int m = 0; m < 4; ++m)
#pragma unroll
    for (int n = 0; n < 4; ++n) acc[m][n] = (f32x4){0.f, 0.f, 0.f, 0.f};

  const __bf16* Ab = A  + (size_t)(bm * BM) * K;
  const __bf16* Bb = Bm + (size_t)(bn * BN) * K;

#define STAGE(buf, kt)                                                             \
  do {                                                                             \
    _Pragma("unroll")                                                              \
    for (int j = 0; j < BM * 4 / NTHR; ++j) {                                      \
      int idx = j * NTHR + tid;                                                    \
      int r = idx >> 2, c8 = (idx & 3) * 8;                                        \
      GLOAD_LDS16(Ab + (size_t)r * K + (kt) * 32 + c8, (char*)At[buf] + idx * 16); \
    }                                                                              \
    _Pragma("unroll")                                                              \
    for (int j = 0; j < BN * 4 / NTHR; ++j) {                                      \
      int idx = j * NTHR + tid;                                                    \
      int r = idx >> 2, c8 = (idx & 3) * 8;                                        \
      GLOAD_LDS16(Bb + (size_t)r * K + (kt) * 32 + c8, (char*)Bt[buf] + idx * 16); \
    }                                                                              \
  } while (0)

  const int nkt = K >> 5;
  STAGE(0, 0);                 // prologue: first tile in flight

  int cur = 0;
  for (int kt = 0; kt < nkt; ++kt) {
    // Loads for buf[cur] were issued one iteration ago (or in the prologue)
    // and have had the whole previous compute phase to fly.
    asm volatile("s_waitcnt vmcnt(0)" ::: "memory");
    __builtin_amdgcn_s_barrier();   // raw: no compiler-inserted drain

    // ds_read current fragments FIRST (no outstanding vmem in program order
    // -> compiler inserts no conservative vmcnt before these)
    bf16x8 af[4], bfr[4];
    const bf16x8* Ap = (const bf16x8*)At[cur];
    const bf16x8* Bp = (const bf16x8*)Bt[cur];
#pragma unroll
    for (int m = 0; m < 4; ++m) af[m]  = Ap[(wr * 64 + m * 16 + (lane & 15)) * 4 + (lane >> 4)];
#pragma unroll
    for (int n = 0; n < 4; ++n) bfr[n] = Bp[(wc * 64 + n * 16 + (lane & 15)) * 4 + (lane >> 4)];
    __builtin_amdgcn_sched_barrier(0);   // pin: ds_reads issued before STAGE

    if (kt + 1 < nkt) STAGE(cur ^ 1, kt + 1);   // next tile flies across the barrier
    __builtin_amdgcn_sched_barrier(0);   // pin: STAGE issued before MFMA cluster

#pragma unroll
    for (int m = 0; m < 4; ++m)
#pragma unroll
      for (int n = 0; n < 4; ++n)
        acc[m][n] = __builtin_amdgcn_mfma_f32_16x16x32_bf16(af[m], bfr[n], acc[m][n], 0, 0, 0);

    cur ^= 1;
  }
#undef STAGE

  // epilogue: C/D layout col=lane&15, row=(lane>>4)*4+j (m89/m91-verified)
#pragma unroll
  for (int m = 0; m < 4; ++m) {
    const int row0 = bm * BM + wr * 64 + m * 16 + ((lane >> 4) << 2);
#pragma unroll
    for (int n = 0; n < 4; ++n) {
      const int col = bn * BN + wc * 64 + n * 16 + (lane & 15);
      if (EPI == 0) {
        if (col < 1000) {
          const float bz = bias1[col];
#pragma unroll
          for (int j = 0; j < 4; ++j)
            outF[(size_t)(row0 + j) * 1000 + col] = acc[m][n][j] + bz;
        } else if (col >= 1024) {
          const float bz = bias2[col - 1024];
#pragma unroll
          for (int j = 0; j < 4; ++j) {
            float v = acc[m][n][j] + bz;
            outB[(size_t)(row0 + j) * 1024 + (col - 1024)] = (__bf16)fmaxf(v, 0.f);
          }
        }
      } else if (EPI == 1) {
        const float bz = bias1[col];
#pragma unroll
        for (int j = 0; j < 4; ++j) {
          float v = acc[m][n][j] + bz;
          outB[(size_t)(row0 + j) * 1024 + col] = (__bf16)fmaxf(v, 0.f);
        }
      } else {
        if (col < 1000) {
#pragma unroll
          for (int j = 0; j < 4; ++j)
            outF[(size_t)(row0 + j) * 1000 + col] = acc[m][n][j];
        }
      }
    }
  }
}

// ---------------- launch ----------------

extern "C" void kernel_launch(void* const* d_in, const int* in_sizes, int n_in,
                              void* d_out, int out_size, void* d_ws, size_t ws_size,
                              hipStream_t stream) {
  const float* image = (const float*)d_in[0];
  const float* wemb  = (const float*)d_in[1];
  const float* Wcls  = (const float*)d_in[2];
  const float* bcls  = (const float*)d_in[3];
  const float* Wvis  = (const float*)d_in[4];
  const float* bvis  = (const float*)d_in[5];
  const float* Wsem  = (const float*)d_in[6];
  const float* bsem  = (const float*)d_in[7];

  float* logits = (float*)d_out;                  // [2048][1000]
  float* scores = logits + (size_t)2048 * 1000;   // [2048][1000]

  char* ws = (char*)d_ws;
  __bf16* imgB  = (__bf16*)(ws);
  __bf16* WcomB = (__bf16*)(ws + 8388608);
  __bf16* Vb    = (__bf16*)(ws + 16777216);
  __bf16* Sb    = (__bf16*)(ws + 20971520);
  __bf16* wordB = (__bf16*)(ws + 23068672);
  __bf16* WsemB = (__bf16*)(ws + 23724032);

  cvt_all_k<<<6656, 256, 0, stream>>>(image, Wcls, Wvis, wemb, Wsem,
                                      imgB, WcomB, wordB, WsemB);

  // fused logits+V: [2048 x 2048pad] = imgB @ WcomB^T, K=2048, 128x128 tiles, 256 blocks
  gemm_bt_k<2, 2, 0><<<dim3(16, 16), 256, 0, stream>>>(imgB, WcomB, bcls, bvis, logits, Vb, 2048);
  // S: [1024pad x 1024] = wordB @ WsemB^T, K=320, 64x128 tiles, 128 blocks
  gemm_bt_k<1, 2, 1><<<dim3(8, 16), 128, 0, stream>>>(wordB, WsemB, bsem, nullptr, nullptr, Sb, 320);
  // scores: [2048 x 1024pad] = Vb @ Sb^T, K=1024, 64x128 tiles, 256 blocks
  gemm_bt_k<1, 2, 2><<<dim3(8, 32), 128, 0, stream>>>(Vb, Sb, nullptr, nullptr, scores, nullptr, 1024);
}

// Round 4
// 66.254 us; speedup vs baseline: 1.4229x; 1.1302x over previous
//
#include <hip/hip_runtime.h>
#include <hip/hip_bf16.h>

// DeViSE bf16-MFMA. Round 4: + T2 LDS chunk-swizzle (linear dest, swizzled
// global source + swizzled read slots), depth-2 prefetch (3 LDS buffers,
// counted vmcnt), parametrized wave tiles so every GEMM fills all 4 SIMDs.
//
// Workspace layout (bytes):
//   imgB  [2048][2048] bf16 @ 0
//   WcomB [2048][2048] bf16 @ 8,388,608   (rows 0-999 Wcls, 1000-1023 zero, 1024+ Wvis)
//   Vb    [2048][1024] bf16 @ 16,777,216
//   Sb    [1024][1024] bf16 @ 20,971,520
//   wordB [1024][320]  bf16 @ 23,068,672  (zero-pad rows>=1000, cols>=300)
//   WsemB [1024][320]  bf16 @ 23,724,032  (zero-pad cols>=300)

typedef __bf16 bf16x8 __attribute__((ext_vector_type(8)));
typedef float  f32x4  __attribute__((ext_vector_type(4)));

#define GLOAD_LDS16(gptr, lptr)                                                     \
  __builtin_amdgcn_global_load_lds((__attribute__((address_space(1))) void*)(gptr), \
                                   (__attribute__((address_space(3))) void*)(lptr), \
                                   16, 0, 0)

// Involutive 16B-chunk swizzle within a [rows][32]bf16 tile (chunk = r*4+hi).
// Spreads 16 consecutive rows at fixed hi over all 8 LDS bank-groups.
__device__ __forceinline__ int sig(int c) {
  int q = (c >> 3) & 3;
  return c ^ (((q & 1) << 2) | (q & 3));
}

template <int N> __device__ __forceinline__ void wait_vmcnt() {
  if constexpr (N == 0) asm volatile("s_waitcnt vmcnt(0)" ::: "memory");
  else if constexpr (N == 2) asm volatile("s_waitcnt vmcnt(2)" ::: "memory");
  else if constexpr (N == 3) asm volatile("s_waitcnt vmcnt(3)" ::: "memory");
  else if constexpr (N == 4) asm volatile("s_waitcnt vmcnt(4)" ::: "memory");
  else static_assert(N == 0 || N == 2 || N == 3 || N == 4, "add vmcnt case");
}

// ---------------- merged convert kernel ----------------
__device__ __forceinline__ bf16x8 cvt8(const float* src) {
  const float4* s = (const float4*)src;
  float4 x = s[0], y = s[1];
  bf16x8 o;
  o[0] = (__bf16)x.x; o[1] = (__bf16)x.y; o[2] = (__bf16)x.z; o[3] = (__bf16)x.w;
  o[4] = (__bf16)y.x; o[5] = (__bf16)y.y; o[6] = (__bf16)y.z; o[7] = (__bf16)y.w;
  return o;
}

__global__ void cvt_all_k(const float* __restrict__ image, const float* __restrict__ Wcls,
                          const float* __restrict__ Wvis, const float* __restrict__ wemb,
                          const float* __restrict__ Wsem,
                          __bf16* __restrict__ imgB, __bf16* __restrict__ WcomB,
                          __bf16* __restrict__ wordB, __bf16* __restrict__ WsemB) {
  const int blk = blockIdx.x, tid = threadIdx.x;
  if (blk < 2048) {
    int i = blk * 256 + tid;
    ((bf16x8*)imgB)[i] = cvt8(image + (size_t)i * 8);
  } else if (blk < 4096) {
    int i = (blk - 2048) * 256 + tid;
    int row = i >> 8, cc = (i & 255) * 8;
    bf16x8 o;
    if (row < 1000)       o = cvt8(Wcls + (size_t)row * 2048 + cc);
    else if (row >= 1024) o = cvt8(Wvis + (size_t)(row - 1024) * 2048 + cc);
    else { for (int j = 0; j < 8; ++j) o[j] = (__bf16)0.f; }
    ((bf16x8*)WcomB)[i] = o;
  } else if (blk < 5376) {
    int i = (blk - 4096) * 256 + tid;
    int r = i / 320, c = i - r * 320;
    float v = (r < 1000 && c < 300) ? wemb[(size_t)r * 300 + c] : 0.f;
    wordB[i] = (__bf16)v;
  } else {
    int i = (blk - 5376) * 256 + tid;
    int r = i / 320, c = i - r * 320;
    float v = (c < 300) ? Wsem[(size_t)r * 300 + c] : 0.f;
    WsemB[i] = (__bf16)v;
  }
}

// ------- bf16 GEMM, C = A @ B^T, depth-2 counted-vmcnt pipeline, swizzled LDS -------
// Wave tile WTM x WTN, wave grid NWM x NWN; block tile BM x BN, BK = 32.
// EPI 0: col<1000 -> outF=acc+bias1; col>=1024 -> outB=bf16(relu(acc+bias2)) at col-1024
// EPI 1: outB = bf16(relu(acc+bias1))
// EPI 2: col<1000 -> outF = acc
template <int WTM, int WTN, int NWM, int NWN, int EPI>
__global__ void gemm_bt_k(const __bf16* __restrict__ A, const __bf16* __restrict__ Bm,
                          const float* __restrict__ bias1, const float* __restrict__ bias2,
                          float* __restrict__ outF, __bf16* __restrict__ outB, int K) {
  constexpr int BM = NWM * WTM, BN = NWN * WTN, NTHR = NWM * NWN * 64;
  constexpr int AM = WTM / 16, AN = WTN / 16;
  constexpr int LA = BM * 4 / NTHR, LB = BN * 4 / NTHR, LPS = LA + LB;
  __shared__ __align__(16) __bf16 At[3][BM * 32];
  __shared__ __align__(16) __bf16 Bt[3][BN * 32];
  const int tid  = threadIdx.x;
  const int lane = tid & 63;
  const int wv   = tid >> 6;
  const int wvr  = wv / NWN, wvc = wv % NWN;
  const int bm = blockIdx.y, bn = blockIdx.x;

  f32x4 acc[AM][AN];
#pragma unroll
  for (int m = 0; m < AM; ++m)
#pragma unroll
    for (int n = 0; n < AN; ++n) acc[m][n] = (f32x4){0.f, 0.f, 0.f, 0.f};

  // Swizzled read slots are kt-invariant: precompute.
  int slotA[AM], slotB[AN];
#pragma unroll
  for (int m = 0; m < AM; ++m) {
    int r = wvr * WTM + m * 16 + (lane & 15);
    slotA[m] = sig(r * 4 + (lane >> 4));
  }
#pragma unroll
  for (int n = 0; n < AN; ++n) {
    int r = wvc * WTN + n * 16 + (lane & 15);
    slotB[n] = sig(r * 4 + (lane >> 4));
  }

  const __bf16* Ab = A  + (size_t)(bm * BM) * K;
  const __bf16* Bb = Bm + (size_t)(bn * BN) * K;

#define STAGE(buf, kt)                                                   \
  do {                                                                   \
    _Pragma("unroll")                                                    \
    for (int j = 0; j < LA; ++j) {                                       \
      int s = j * NTHR + tid;                                            \
      int c = sig(s);                                                    \
      GLOAD_LDS16(Ab + (size_t)(c >> 2) * K + (kt) * 32 + (c & 3) * 8,   \
                  (char*)At[buf] + s * 16);                              \
    }                                                                    \
    _Pragma("unroll")                                                    \
    for (int j = 0; j < LB; ++j) {                                       \
      int s = j * NTHR + tid;                                            \
      int c = sig(s);                                                    \
      GLOAD_LDS16(Bb + (size_t)(c >> 2) * K + (kt) * 32 + (c & 3) * 8,   \
                  (char*)Bt[buf] + s * 16);                              \
    }                                                                    \
  } while (0)

  const int nkt = K >> 5;          // >= 10 for all our shapes
  STAGE(0, 0);
  STAGE(1, 1);

  int cur = 0;
  for (int kt = 0; kt < nkt; ++kt) {
    if (kt + 1 < nkt) wait_vmcnt<LPS>();   // tile kt done, kt+1 still in flight
    else              wait_vmcnt<0>();     // last tile: full drain
    __builtin_amdgcn_s_barrier();

    bf16x8 af[AM], bfr[AN];
    const bf16x8* Ap = (const bf16x8*)At[cur];
    const bf16x8* Bp = (const bf16x8*)Bt[cur];
#pragma unroll
    for (int m = 0; m < AM; ++m) af[m]  = Ap[slotA[m]];
#pragma unroll
    for (int n = 0; n < AN; ++n) bfr[n] = Bp[slotB[n]];
    __builtin_amdgcn_sched_barrier(0);   // ds_reads issued before STAGE

    if (kt + 2 < nkt) {
      int nb = cur + 2; if (nb >= 3) nb -= 3;
      STAGE(nb, kt + 2);                 // flies across the next 2 barriers
    }
    __builtin_amdgcn_sched_barrier(0);   // STAGE issued before MFMA cluster

#pragma unroll
    for (int m = 0; m < AM; ++m)
#pragma unroll
      for (int n = 0; n < AN; ++n)
        acc[m][n] = __builtin_amdgcn_mfma_f32_16x16x32_bf16(af[m], bfr[n], acc[m][n], 0, 0, 0);

    ++cur; if (cur >= 3) cur = 0;
  }
#undef STAGE

  // epilogue: C/D layout col=lane&15, row=(lane>>4)*4+j (m89/m91-verified)
#pragma unroll
  for (int m = 0; m < AM; ++m) {
    const int row0 = bm * BM + wvr * WTM + m * 16 + ((lane >> 4) << 2);
#pragma unroll
    for (int n = 0; n < AN; ++n) {
      const int col = bn * BN + wvc * WTN + n * 16 + (lane & 15);
      if (EPI == 0) {
        if (col < 1000) {
          const float bz = bias1[col];
#pragma unroll
          for (int j = 0; j < 4; ++j)
            outF[(size_t)(row0 + j) * 1000 + col] = acc[m][n][j] + bz;
        } else if (col >= 1024) {
          const float bz = bias2[col - 1024];
#pragma unroll
          for (int j = 0; j < 4; ++j) {
            float v = acc[m][n][j] + bz;
            outB[(size_t)(row0 + j) * 1024 + (col - 1024)] = (__bf16)fmaxf(v, 0.f);
          }
        }
      } else if (EPI == 1) {
        const float bz = bias1[col];
#pragma unroll
        for (int j = 0; j < 4; ++j) {
          float v = acc[m][n][j] + bz;
          outB[(size_t)(row0 + j) * 1024 + col] = (__bf16)fmaxf(v, 0.f);
        }
      } else {
        if (col < 1000) {
#pragma unroll
          for (int j = 0; j < 4; ++j)
            outF[(size_t)(row0 + j) * 1000 + col] = acc[m][n][j];
        }
      }
    }
  }
}

// ---------------- launch ----------------

extern "C" void kernel_launch(void* const* d_in, const int* in_sizes, int n_in,
                              void* d_out, int out_size, void* d_ws, size_t ws_size,
                              hipStream_t stream) {
  const float* image = (const float*)d_in[0];
  const float* wemb  = (const float*)d_in[1];
  const float* Wcls  = (const float*)d_in[2];
  const float* bcls  = (const float*)d_in[3];
  const float* Wvis  = (const float*)d_in[4];
  const float* bvis  = (const float*)d_in[5];
  const float* Wsem  = (const float*)d_in[6];
  const float* bsem  = (const float*)d_in[7];

  float* logits = (float*)d_out;                  // [2048][1000]
  float* scores = logits + (size_t)2048 * 1000;   // [2048][1000]

  char* ws = (char*)d_ws;
  __bf16* imgB  = (__bf16*)(ws);
  __bf16* WcomB = (__bf16*)(ws + 8388608);
  __bf16* Vb    = (__bf16*)(ws + 16777216);
  __bf16* Sb    = (__bf16*)(ws + 20971520);
  __bf16* wordB = (__bf16*)(ws + 23068672);
  __bf16* WsemB = (__bf16*)(ws + 23724032);

  cvt_all_k<<<6656, 256, 0, stream>>>(image, Wcls, Wvis, wemb, Wsem,
                                      imgB, WcomB, wordB, WsemB);

  // fused logits+V: [2048 x 2048pad] = imgB @ WcomB^T, K=2048
  // 128x128 tile, 4 waves of 64x64, grid 256 = 1 block/CU
  gemm_bt_k<64, 64, 2, 2, 0><<<dim3(16, 16), 256, 0, stream>>>(
      imgB, WcomB, bcls, bvis, logits, Vb, 2048);
  // S: [1024pad x 1024] = wordB @ WsemB^T, K=320
  // 64x64 tile, 4 waves of 32x32, grid (16,16) = 256 blocks
  gemm_bt_k<32, 32, 2, 2, 1><<<dim3(16, 16), 256, 0, stream>>>(
      wordB, WsemB, bsem, nullptr, nullptr, Sb, 320);
  // scores: [2048 x 1024pad] = Vb @ Sb^T, K=1024
  // 64x128 tile, 4 waves of 32x64, grid (8,32) = 256 blocks
  gemm_bt_k<32, 64, 2, 2, 2><<<dim3(8, 32), 256, 0, stream>>>(
      Vb, Sb, nullptr, nullptr, scores, nullptr, 1024);
}

// Round 5
// 62.515 us; speedup vs baseline: 1.5080x; 1.0598x over previous
//
#include <hip/hip_runtime.h>
#include <hip/hip_bf16.h>

// DeViSE bf16-MFMA. Round 5: 2 blocks/CU for the big GEMMs (64x128 / 64x64
// tiles, grid 512) so cross-block wave overlap (m114) hides lgkmcnt/MFMA
// chains and barrier gaps. Keeps R4's swizzled LDS + depth-2 counted-vmcnt.
//
// Workspace layout (bytes):
//   imgB  [2048][2048] bf16 @ 0
//   WcomB [2048][2048] bf16 @ 8,388,608   (rows 0-999 Wcls, 1000-1023 zero, 1024+ Wvis)
//   Vb    [2048][1024] bf16 @ 16,777,216
//   Sb    [1024][1024] bf16 @ 20,971,520
//   wordB [1024][320]  bf16 @ 23,068,672  (zero-pad rows>=1000, cols>=300)
//   WsemB [1024][320]  bf16 @ 23,724,032  (zero-pad cols>=300)

typedef __bf16 bf16x8 __attribute__((ext_vector_type(8)));
typedef float  f32x4  __attribute__((ext_vector_type(4)));

#define GLOAD_LDS16(gptr, lptr)                                                     \
  __builtin_amdgcn_global_load_lds((__attribute__((address_space(1))) void*)(gptr), \
                                   (__attribute__((address_space(3))) void*)(lptr), \
                                   16, 0, 0)

// Involutive 16B-chunk swizzle within a [rows][32]bf16 tile (chunk = r*4+hi).
__device__ __forceinline__ int sig(int c) {
  int q = (c >> 3) & 3;
  return c ^ (((q & 1) << 2) | (q & 3));
}

template <int N> __device__ __forceinline__ void wait_vmcnt() {
  if constexpr (N == 0) asm volatile("s_waitcnt vmcnt(0)" ::: "memory");
  else if constexpr (N == 2) asm volatile("s_waitcnt vmcnt(2)" ::: "memory");
  else if constexpr (N == 3) asm volatile("s_waitcnt vmcnt(3)" ::: "memory");
  else if constexpr (N == 4) asm volatile("s_waitcnt vmcnt(4)" ::: "memory");
  else static_assert(N == 0 || N == 2 || N == 3 || N == 4, "add vmcnt case");
}

// ---------------- merged convert kernel ----------------
__device__ __forceinline__ bf16x8 cvt8(const float* src) {
  const float4* s = (const float4*)src;
  float4 x = s[0], y = s[1];
  bf16x8 o;
  o[0] = (__bf16)x.x; o[1] = (__bf16)x.y; o[2] = (__bf16)x.z; o[3] = (__bf16)x.w;
  o[4] = (__bf16)y.x; o[5] = (__bf16)y.y; o[6] = (__bf16)y.z; o[7] = (__bf16)y.w;
  return o;
}

__global__ void cvt_all_k(const float* __restrict__ image, const float* __restrict__ Wcls,
                          const float* __restrict__ Wvis, const float* __restrict__ wemb,
                          const float* __restrict__ Wsem,
                          __bf16* __restrict__ imgB, __bf16* __restrict__ WcomB,
                          __bf16* __restrict__ wordB, __bf16* __restrict__ WsemB) {
  const int blk = blockIdx.x, tid = threadIdx.x;
  if (blk < 2048) {
    int i = blk * 256 + tid;
    ((bf16x8*)imgB)[i] = cvt8(image + (size_t)i * 8);
  } else if (blk < 4096) {
    int i = (blk - 2048) * 256 + tid;
    int row = i >> 8, cc = (i & 255) * 8;
    bf16x8 o;
    if (row < 1000)       o = cvt8(Wcls + (size_t)row * 2048 + cc);
    else if (row >= 1024) o = cvt8(Wvis + (size_t)(row - 1024) * 2048 + cc);
    else { for (int j = 0; j < 8; ++j) o[j] = (__bf16)0.f; }
    ((bf16x8*)WcomB)[i] = o;
  } else if (blk < 5376) {
    int i = (blk - 4096) * 256 + tid;
    int r = i / 320, c = i - r * 320;
    float v = (r < 1000 && c < 300) ? wemb[(size_t)r * 300 + c] : 0.f;
    wordB[i] = (__bf16)v;
  } else {
    int i = (blk - 5376) * 256 + tid;
    int r = i / 320, c = i - r * 320;
    float v = (c < 300) ? Wsem[(size_t)r * 300 + c] : 0.f;
    WsemB[i] = (__bf16)v;
  }
}

// ------- bf16 GEMM, C = A @ B^T, depth-2 counted-vmcnt pipeline, swizzled LDS -------
// Wave tile WTM x WTN, wave grid NWM x NWN; block tile BM x BN, BK = 32.
// EPI 0: col<1000 -> outF=acc+bias1; col>=1024 -> outB=bf16(relu(acc+bias2)) at col-1024
// EPI 1: outB = bf16(relu(acc+bias1))
// EPI 2: col<1000 -> outF = acc
template <int WTM, int WTN, int NWM, int NWN, int EPI>
__global__ void gemm_bt_k(const __bf16* __restrict__ A, const __bf16* __restrict__ Bm,
                          const float* __restrict__ bias1, const float* __restrict__ bias2,
                          float* __restrict__ outF, __bf16* __restrict__ outB, int K) {
  constexpr int BM = NWM * WTM, BN = NWN * WTN, NTHR = NWM * NWN * 64;
  constexpr int AM = WTM / 16, AN = WTN / 16;
  constexpr int LA = BM * 4 / NTHR, LB = BN * 4 / NTHR, LPS = LA + LB;
  __shared__ __align__(16) __bf16 At[3][BM * 32];
  __shared__ __align__(16) __bf16 Bt[3][BN * 32];
  const int tid  = threadIdx.x;
  const int lane = tid & 63;
  const int wv   = tid >> 6;
  const int wvr  = wv / NWN, wvc = wv % NWN;
  const int bm = blockIdx.y, bn = blockIdx.x;

  f32x4 acc[AM][AN];
#pragma unroll
  for (int m = 0; m < AM; ++m)
#pragma unroll
    for (int n = 0; n < AN; ++n) acc[m][n] = (f32x4){0.f, 0.f, 0.f, 0.f};

  // Swizzled read slots are kt-invariant: precompute.
  int slotA[AM], slotB[AN];
#pragma unroll
  for (int m = 0; m < AM; ++m) {
    int r = wvr * WTM + m * 16 + (lane & 15);
    slotA[m] = sig(r * 4 + (lane >> 4));
  }
#pragma unroll
  for (int n = 0; n < AN; ++n) {
    int r = wvc * WTN + n * 16 + (lane & 15);
    slotB[n] = sig(r * 4 + (lane >> 4));
  }

  const __bf16* Ab = A  + (size_t)(bm * BM) * K;
  const __bf16* Bb = Bm + (size_t)(bn * BN) * K;

#define STAGE(buf, kt)                                                   \
  do {                                                                   \
    _Pragma("unroll")                                                    \
    for (int j = 0; j < LA; ++j) {                                       \
      int s = j * NTHR + tid;                                            \
      int c = sig(s);                                                    \
      GLOAD_LDS16(Ab + (size_t)(c >> 2) * K + (kt) * 32 + (c & 3) * 8,   \
                  (char*)At[buf] + s * 16);                              \
    }                                                                    \
    _Pragma("unroll")                                                    \
    for (int j = 0; j < LB; ++j) {                                       \
      int s = j * NTHR + tid;                                            \
      int c = sig(s);                                                    \
      GLOAD_LDS16(Bb + (size_t)(c >> 2) * K + (kt) * 32 + (c & 3) * 8,   \
                  (char*)Bt[buf] + s * 16);                              \
    }                                                                    \
  } while (0)

  const int nkt = K >> 5;          // >= 10 for all our shapes
  STAGE(0, 0);
  STAGE(1, 1);

  int cur = 0;
  for (int kt = 0; kt < nkt; ++kt) {
    if (kt + 1 < nkt) wait_vmcnt<LPS>();   // tile kt done, kt+1 still in flight
    else              wait_vmcnt<0>();     // last tile: full drain
    __builtin_amdgcn_s_barrier();

    bf16x8 af[AM], bfr[AN];
    const bf16x8* Ap = (const bf16x8*)At[cur];
    const bf16x8* Bp = (const bf16x8*)Bt[cur];
#pragma unroll
    for (int m = 0; m < AM; ++m) af[m]  = Ap[slotA[m]];
#pragma unroll
    for (int n = 0; n < AN; ++n) bfr[n] = Bp[slotB[n]];
    __builtin_amdgcn_sched_barrier(0);   // ds_reads issued before STAGE

    if (kt + 2 < nkt) {
      int nb = cur + 2; if (nb >= 3) nb -= 3;
      STAGE(nb, kt + 2);                 // flies across the next 2 barriers
    }
    __builtin_amdgcn_sched_barrier(0);   // STAGE issued before MFMA cluster

#pragma unroll
    for (int m = 0; m < AM; ++m)
#pragma unroll
      for (int n = 0; n < AN; ++n)
        acc[m][n] = __builtin_amdgcn_mfma_f32_16x16x32_bf16(af[m], bfr[n], acc[m][n], 0, 0, 0);

    ++cur; if (cur >= 3) cur = 0;
  }
#undef STAGE

  // epilogue: C/D layout col=lane&15, row=(lane>>4)*4+j (m89/m91-verified)
#pragma unroll
  for (int m = 0; m < AM; ++m) {
    const int row0 = bm * BM + wvr * WTM + m * 16 + ((lane >> 4) << 2);
#pragma unroll
    for (int n = 0; n < AN; ++n) {
      const int col = bn * BN + wvc * WTN + n * 16 + (lane & 15);
      if (EPI == 0) {
        if (col < 1000) {
          const float bz = bias1[col];
#pragma unroll
          for (int j = 0; j < 4; ++j)
            outF[(size_t)(row0 + j) * 1000 + col] = acc[m][n][j] + bz;
        } else if (col >= 1024) {
          const float bz = bias2[col - 1024];
#pragma unroll
          for (int j = 0; j < 4; ++j) {
            float v = acc[m][n][j] + bz;
            outB[(size_t)(row0 + j) * 1024 + (col - 1024)] = (__bf16)fmaxf(v, 0.f);
          }
        }
      } else if (EPI == 1) {
        const float bz = bias1[col];
#pragma unroll
        for (int j = 0; j < 4; ++j) {
          float v = acc[m][n][j] + bz;
          outB[(size_t)(row0 + j) * 1024 + col] = (__bf16)fmaxf(v, 0.f);
        }
      } else {
        if (col < 1000) {
#pragma unroll
          for (int j = 0; j < 4; ++j)
            outF[(size_t)(row0 + j) * 1000 + col] = acc[m][n][j];
        }
      }
    }
  }
}

// ---------------- launch ----------------

extern "C" void kernel_launch(void* const* d_in, const int* in_sizes, int n_in,
                              void* d_out, int out_size, void* d_ws, size_t ws_size,
                              hipStream_t stream) {
  const float* image = (const float*)d_in[0];
  const float* wemb  = (const float*)d_in[1];
  const float* Wcls  = (const float*)d_in[2];
  const float* bcls  = (const float*)d_in[3];
  const float* Wvis  = (const float*)d_in[4];
  const float* bvis  = (const float*)d_in[5];
  const float* Wsem  = (const float*)d_in[6];
  const float* bsem  = (const float*)d_in[7];

  float* logits = (float*)d_out;                  // [2048][1000]
  float* scores = logits + (size_t)2048 * 1000;   // [2048][1000]

  char* ws = (char*)d_ws;
  __bf16* imgB  = (__bf16*)(ws);
  __bf16* WcomB = (__bf16*)(ws + 8388608);
  __bf16* Vb    = (__bf16*)(ws + 16777216);
  __bf16* Sb    = (__bf16*)(ws + 20971520);
  __bf16* wordB = (__bf16*)(ws + 23068672);
  __bf16* WsemB = (__bf16*)(ws + 23724032);

  cvt_all_k<<<6656, 256, 0, stream>>>(image, Wcls, Wvis, wemb, Wsem,
                                      imgB, WcomB, wordB, WsemB);

  // fused logits+V: [2048 x 2048pad] = imgB @ WcomB^T, K=2048
  // 64x128 tile, 4 waves of 32x64, grid (16,32) = 512 blocks = 2 blocks/CU
  gemm_bt_k<32, 64, 2, 2, 0><<<dim3(16, 32), 256, 0, stream>>>(
      imgB, WcomB, bcls, bvis, logits, Vb, 2048);
  // S: [1024pad x 1024] = wordB @ WsemB^T, K=320
  // 64x64 tile, 4 waves of 32x32, grid (16,16) = 256 blocks
  gemm_bt_k<32, 32, 2, 2, 1><<<dim3(16, 16), 256, 0, stream>>>(
      wordB, WsemB, bsem, nullptr, nullptr, Sb, 320);
  // scores: [2048 x 1024pad] = Vb @ Sb^T, K=1024
  // 64x64 tile, 4 waves of 32x32, grid (16,32) = 512 blocks = 2 blocks/CU
  gemm_bt_k<32, 32, 2, 2, 2><<<dim3(16, 32), 256, 0, stream>>>(
      Vb, Sb, nullptr, nullptr, scores, nullptr, 1024);
}

// Round 6
// 51.303 us; speedup vs baseline: 1.8376x; 1.2186x over previous
//
#include <hip/hip_runtime.h>
#include <hip/hip_bf16.h>

// DeViSE bf16-MFMA. Round 6: BK=64 (2x MFMA per sync phase, half the barriers),
// 2-buffer pipeline with 48KB dynamic LDS -> 3 blocks/CU, S-GEMM merged into the
// fused dispatch as extra blocks (removes a serial dispatch), 8-chunk XOR swizzle.
//
// Workspace layout (bytes):
//   imgB  [2048][2048] bf16 @ 0
//   WcomB [2048][2048] bf16 @ 8,388,608   (rows 0-999 Wcls, 1000-1023 zero, 1024+ Wvis)
//   Vb    [2048][1024] bf16 @ 16,777,216
//   Sb    [1024][1024] bf16 @ 20,971,520
//   wordB [1024][320]  bf16 @ 23,068,672  (zero-pad rows>=1000, cols>=300)
//   WsemB [1024][320]  bf16 @ 23,724,032  (zero-pad cols>=300)

typedef __bf16 bf16x8 __attribute__((ext_vector_type(8)));
typedef float  f32x4  __attribute__((ext_vector_type(4)));

#define GLOAD_LDS16(gptr, lptr)                                                     \
  __builtin_amdgcn_global_load_lds((__attribute__((address_space(1))) void*)(gptr), \
                                   (__attribute__((address_space(3))) void*)(lptr), \
                                   16, 0, 0)

// ---------------- merged convert kernel ----------------
__device__ __forceinline__ bf16x8 cvt8(const float* src) {
  const float4* s = (const float4*)src;
  float4 x = s[0], y = s[1];
  bf16x8 o;
  o[0] = (__bf16)x.x; o[1] = (__bf16)x.y; o[2] = (__bf16)x.z; o[3] = (__bf16)x.w;
  o[4] = (__bf16)y.x; o[5] = (__bf16)y.y; o[6] = (__bf16)y.z; o[7] = (__bf16)y.w;
  return o;
}

__global__ void cvt_all_k(const float* __restrict__ image, const float* __restrict__ Wcls,
                          const float* __restrict__ Wvis, const float* __restrict__ wemb,
                          const float* __restrict__ Wsem,
                          __bf16* __restrict__ imgB, __bf16* __restrict__ WcomB,
                          __bf16* __restrict__ wordB, __bf16* __restrict__ WsemB) {
  const int blk = blockIdx.x, tid = threadIdx.x;
  if (blk < 2048) {
    int i = blk * 256 + tid;
    ((bf16x8*)imgB)[i] = cvt8(image + (size_t)i * 8);
  } else if (blk < 4096) {
    int i = (blk - 2048) * 256 + tid;
    int row = i >> 8, cc = (i & 255) * 8;
    bf16x8 o;
    if (row < 1000)       o = cvt8(Wcls + (size_t)row * 2048 + cc);
    else if (row >= 1024) o = cvt8(Wvis + (size_t)(row - 1024) * 2048 + cc);
    else { for (int j = 0; j < 8; ++j) o[j] = (__bf16)0.f; }
    ((bf16x8*)WcomB)[i] = o;
  } else if (blk < 5376) {
    int i = (blk - 4096) * 256 + tid;
    int r = i / 320, c = i - r * 320;
    float v = (r < 1000 && c < 300) ? wemb[(size_t)r * 300 + c] : 0.f;
    wordB[i] = (__bf16)v;
  } else {
    int i = (blk - 5376) * 256 + tid;
    int r = i / 320, c = i - r * 320;
    float v = (c < 300) ? Wsem[(size_t)r * 300 + c] : 0.f;
    WsemB[i] = (__bf16)v;
  }
}

// ------- bf16 GEMM body, C = A @ B^T, BK=64, 2-buffer counted pipeline -------
// LDS layout in smem: At[2][BM*64] bf16, then Bt[2][BN*64] bf16.
// Chunk swizzle: logical 16B chunk (r, c) of a [rows][64]bf16 tile stored at
// slot r*8 + (c ^ (r&7))  -> 16 consecutive rows at fixed c spread over all
// 8 bank groups (2-way = free). Staging pre-swizzles the GLOBAL source; LDS
// dest stays linear (global_load_lds requirement).
// EPI 0: col<1000 -> outF=acc+bias1; col>=1024 -> outB=bf16(relu(acc+bias2)) at col-1024
// EPI 1: outB = bf16(relu(acc+bias1))
// EPI 2: col<1000 -> outF = acc
template <int WTM, int WTN, int NWM, int NWN, int EPI>
__device__ __forceinline__ void gemm_body(char* smem,
    const __bf16* __restrict__ A, const __bf16* __restrict__ Bm,
    const float* __restrict__ bias1, const float* __restrict__ bias2,
    float* __restrict__ outF, __bf16* __restrict__ outB, int K, int bm, int bn) {
  constexpr int BM = NWM * WTM, BN = NWN * WTN, NTHR = NWM * NWN * 64;
  constexpr int AM = WTM / 16, AN = WTN / 16;
  constexpr int LA = BM * 8 / NTHR, LB = BN * 8 / NTHR;   // 16B chunks per thread
  char* AtB = smem;                        // 2 bufs x BM*128 bytes
  char* BtB = smem + 2 * BM * 128;         // 2 bufs x BN*128 bytes
  const int tid  = threadIdx.x;
  const int lane = tid & 63;
  const int wv   = tid >> 6;
  const int wvr  = wv / NWN, wvc = wv % NWN;

  f32x4 acc[AM][AN];
#pragma unroll
  for (int m = 0; m < AM; ++m)
#pragma unroll
    for (int n = 0; n < AN; ++n) acc[m][n] = (f32x4){0.f, 0.f, 0.f, 0.f};

  // kt-invariant swizzled read slots (bf16x8 index within a buffer)
  int slotA[2][AM], slotB[2][AN];
#pragma unroll
  for (int kh = 0; kh < 2; ++kh) {
#pragma unroll
    for (int m = 0; m < AM; ++m) {
      int r = wvr * WTM + m * 16 + (lane & 15);
      slotA[kh][m] = r * 8 + ((kh * 4 + (lane >> 4)) ^ (r & 7));
    }
#pragma unroll
    for (int n = 0; n < AN; ++n) {
      int r = wvc * WTN + n * 16 + (lane & 15);
      slotB[kh][n] = r * 8 + ((kh * 4 + (lane >> 4)) ^ (r & 7));
    }
  }

  const __bf16* Ab = A  + (size_t)(bm * BM) * K;
  const __bf16* Bb = Bm + (size_t)(bn * BN) * K;

#define STAGE64(buf, kt)                                                       \
  do {                                                                         \
    _Pragma("unroll")                                                          \
    for (int j = 0; j < LA; ++j) {                                             \
      int s = j * NTHR + tid;                                                  \
      int r = s >> 3, c = (s & 7) ^ (r & 7);                                   \
      GLOAD_LDS16(Ab + (size_t)r * K + (kt) * 64 + c * 8,                      \
                  AtB + (buf) * (BM * 128) + s * 16);                          \
    }                                                                          \
    _Pragma("unroll")                                                          \
    for (int j = 0; j < LB; ++j) {                                             \
      int s = j * NTHR + tid;                                                  \
      int r = s >> 3, c = (s & 7) ^ (r & 7);                                   \
      GLOAD_LDS16(Bb + (size_t)r * K + (kt) * 64 + c * 8,                      \
                  BtB + (buf) * (BN * 128) + s * 16);                          \
    }                                                                          \
  } while (0)

  const int nkt = K >> 6;
  STAGE64(0, 0);

  int cur = 0;
  for (int kt = 0; kt < nkt; ++kt) {
    // Loads for buf[cur] were issued last iteration (or prologue) and have had
    // the previous ds_read + MFMA cluster to fly.
    asm volatile("s_waitcnt vmcnt(0)" ::: "memory");
    __builtin_amdgcn_s_barrier();

    bf16x8 af[2][AM], bfr[2][AN];
    const bf16x8* Ap = (const bf16x8*)(AtB + cur * (BM * 128));
    const bf16x8* Bp = (const bf16x8*)(BtB + cur * (BN * 128));
#pragma unroll
    for (int kh = 0; kh < 2; ++kh) {
#pragma unroll
      for (int m = 0; m < AM; ++m) af[kh][m]  = Ap[slotA[kh][m]];
#pragma unroll
      for (int n = 0; n < AN; ++n) bfr[kh][n] = Bp[slotB[kh][n]];
    }
    __builtin_amdgcn_sched_barrier(0);   // ds_reads issued before STAGE

    if (kt + 1 < nkt) STAGE64(cur ^ 1, kt + 1);   // flies across MFMA cluster
    __builtin_amdgcn_sched_barrier(0);   // STAGE issued before MFMA cluster

#pragma unroll
    for (int kh = 0; kh < 2; ++kh)
#pragma unroll
      for (int m = 0; m < AM; ++m)
#pragma unroll
        for (int n = 0; n < AN; ++n)
          acc[m][n] = __builtin_amdgcn_mfma_f32_16x16x32_bf16(af[kh][m], bfr[kh][n],
                                                              acc[m][n], 0, 0, 0);
    cur ^= 1;
  }
#undef STAGE64

  // epilogue: C/D layout col=lane&15, row=(lane>>4)*4+j (m89/m91-verified)
#pragma unroll
  for (int m = 0; m < AM; ++m) {
    const int row0 = bm * BM + wvr * WTM + m * 16 + ((lane >> 4) << 2);
#pragma unroll
    for (int n = 0; n < AN; ++n) {
      const int col = bn * BN + wvc * WTN + n * 16 + (lane & 15);
      if (EPI == 0) {
        if (col < 1000) {
          const float bz = bias1[col];
#pragma unroll
          for (int j = 0; j < 4; ++j)
            outF[(size_t)(row0 + j) * 1000 + col] = acc[m][n][j] + bz;
        } else if (col >= 1024) {
          const float bz = bias2[col - 1024];
#pragma unroll
          for (int j = 0; j < 4; ++j) {
            float v = acc[m][n][j] + bz;
            outB[(size_t)(row0 + j) * 1024 + (col - 1024)] = (__bf16)fmaxf(v, 0.f);
          }
        }
      } else if (EPI == 1) {
        const float bz = bias1[col];
#pragma unroll
        for (int j = 0; j < 4; ++j) {
          float v = acc[m][n][j] + bz;
          outB[(size_t)(row0 + j) * 1024 + col] = (__bf16)fmaxf(v, 0.f);
        }
      } else {
        if (col < 1000) {
#pragma unroll
          for (int j = 0; j < 4; ++j)
            outF[(size_t)(row0 + j) * 1000 + col] = acc[m][n][j];
        }
      }
    }
  }
}

// Blocks 0-511: fused logits+V GEMM (64x128 tile). Blocks 512-767: S GEMM (64x64).
__global__ void __launch_bounds__(256, 4)
gemm_merged_k(const __bf16* __restrict__ imgB, const __bf16* __restrict__ WcomB,
              const __bf16* __restrict__ wordB, const __bf16* __restrict__ WsemB,
              const float* __restrict__ bcls, const float* __restrict__ bvis,
              const float* __restrict__ bsem,
              float* __restrict__ logits, __bf16* __restrict__ Vb,
              __bf16* __restrict__ Sb) {
  extern __shared__ char smem[];
  const int blk = blockIdx.x;
  if (blk < 512) {
    gemm_body<32, 64, 2, 2, 0>(smem, imgB, WcomB, bcls, bvis, logits, Vb, 2048,
                               blk >> 4, blk & 15);
  } else {
    const int l = blk - 512;
    gemm_body<32, 32, 2, 2, 1>(smem, wordB, WsemB, bsem, nullptr, nullptr, Sb, 320,
                               l >> 4, l & 15);
  }
}

__global__ void __launch_bounds__(256, 4)
gemm_scores_k(const __bf16* __restrict__ Vb, const __bf16* __restrict__ Sb,
              float* __restrict__ scores) {
  extern __shared__ char smem[];
  const int blk = blockIdx.x;
  gemm_body<32, 32, 2, 2, 2>(smem, Vb, Sb, nullptr, nullptr, scores, nullptr, 1024,
                             blk >> 4, blk & 15);
}

// ---------------- launch ----------------

extern "C" void kernel_launch(void* const* d_in, const int* in_sizes, int n_in,
                              void* d_out, int out_size, void* d_ws, size_t ws_size,
                              hipStream_t stream) {
  const float* image = (const float*)d_in[0];
  const float* wemb  = (const float*)d_in[1];
  const float* Wcls  = (const float*)d_in[2];
  const float* bcls  = (const float*)d_in[3];
  const float* Wvis  = (const float*)d_in[4];
  const float* bvis  = (const float*)d_in[5];
  const float* Wsem  = (const float*)d_in[6];
  const float* bsem  = (const float*)d_in[7];

  float* logits = (float*)d_out;                  // [2048][1000]
  float* scores = logits + (size_t)2048 * 1000;   // [2048][1000]

  char* ws = (char*)d_ws;
  __bf16* imgB  = (__bf16*)(ws);
  __bf16* WcomB = (__bf16*)(ws + 8388608);
  __bf16* Vb    = (__bf16*)(ws + 16777216);
  __bf16* Sb    = (__bf16*)(ws + 20971520);
  __bf16* wordB = (__bf16*)(ws + 23068672);
  __bf16* WsemB = (__bf16*)(ws + 23724032);

  cvt_all_k<<<6656, 256, 0, stream>>>(image, Wcls, Wvis, wemb, Wsem,
                                      imgB, WcomB, wordB, WsemB);

  // fused (512 blocks, 64x128 tiles, K=2048) + S (256 blocks, 64x64, K=320)
  // dynamic LDS = 2*(64+128)*128 = 49152 B  -> 3 blocks/CU
  gemm_merged_k<<<768, 256, 49152, stream>>>(imgB, WcomB, wordB, WsemB,
                                             bcls, bvis, bsem, logits, Vb, Sb);

  // scores: [2048 x 1024pad] = Vb @ Sb^T, K=1024, 64x64 tiles, 512 blocks
  // dynamic LDS = 2*(64+64)*128 = 32768 B
  gemm_scores_k<<<512, 256, 32768, stream>>>(Vb, Sb, scores);
}